// Round 5
// baseline (201.964 us; speedup 1.0000x reference)
//
#include <hip/hip_runtime.h>

// ---------------------------------------------------------------------------
// attention_76089640615954 on MI355X (gfx950)
// x:[1,256,64,64] -> 1x1 conv (3C) -> 11x11 depthwise -> 8-head attn (N=4096,
// d=32, temp=5) -> 1x1 conv + bias -> relu + residual.
// fp16 MFMA (16x16x32) for GEMM-shaped work, fp32 accumulate.
// R3: fixed-shift softmax (Cauchy-Schwarz bound, no online max) -> 53.6us,
//     but VALUBusy 31 / MfmaUtil 12 / occupancy 34.5 (grid-capped at 4
//     blocks/CU) => latency-bound, SIMDs idle 2/3 of the time.
// R4: 512-thread blocks, 8-way key split -> 32 waves/CU (100%); shift folded
//     into MFMA C-operand (kills 16 subs/iter); cvt_pkrtz pack; head-affine
//     block swizzle for per-XCD K/V L2 residency.
// R5: fix cvt_pkrtz return type (__fp16 vector, not _Float16 vector).
// ---------------------------------------------------------------------------

typedef _Float16 f16;
typedef __fp16 hf16x2 __attribute__((ext_vector_type(2)));
typedef _Float16 f16x8 __attribute__((ext_vector_type(8)));
typedef float f32x4 __attribute__((ext_vector_type(4)));

#define HW 4096      // 64*64 pixels
#define NC 256       // channels

#if __has_builtin(__builtin_amdgcn_exp2f)
#define EXP2(x) __builtin_amdgcn_exp2f(x)
#else
#define EXP2(x) exp2f(x)
#endif

static __device__ __forceinline__ f32x4 mfma16(f16x8 a, f16x8 b, f32x4 c) {
  return __builtin_amdgcn_mfma_f32_16x16x32_f16(a, b, c, 0, 0, 0);
}

// --------------------------- prep: weights -> fp16 -------------------------
__global__ __launch_bounds__(256) void k_prep_w(
    const float* __restrict__ wpw, const float* __restrict__ wlin,
    f16* __restrict__ wpw_h, f16* __restrict__ wlin_h,
    int* __restrict__ kmax_bits) {
  int i = blockIdx.x * 256 + threadIdx.x;
  if (i < 8) kmax_bits[i] = 0;  // init for k_norms' atomicMax
  int stride = gridDim.x * 256;
  for (int idx = i; idx < 3 * NC * NC; idx += stride) wpw_h[idx] = (f16)wpw[idx];
  for (int idx = i; idx < NC * NC; idx += stride) wlin_h[idx] = (f16)wlin[idx];
}

// --------------------------- prep: x -> xt[p][c] fp16 ----------------------
__global__ __launch_bounds__(256) void k_transpose_x(
    const float* __restrict__ x, f16* __restrict__ xt) {
  __shared__ float t[32][33];
  int bc = blockIdx.x >> 7;    // 8 channel tiles of 32
  int bp = blockIdx.x & 127;   // 128 pixel tiles of 32
  int tx = threadIdx.x & 31, ty = threadIdx.x >> 5;  // ty 0..7
#pragma unroll
  for (int i = 0; i < 4; i++) {
    int c = bc * 32 + ty + i * 8;
    t[ty + i * 8][tx] = x[c * HW + bp * 32 + tx];
  }
  __syncthreads();
#pragma unroll
  for (int i = 0; i < 4; i++) {
    int p = bp * 32 + ty + i * 8;
    xt[p * NC + bc * 32 + tx] = (f16)t[tx][ty + i * 8];
  }
}

// ------------------- GEMM1: qkv = Wpw[768,256] * x  (+bias) ----------------
__global__ __launch_bounds__(256) void k_gemm_qkv(
    const f16* __restrict__ w, const f16* __restrict__ xt,
    const float* __restrict__ bias, float* __restrict__ out) {
  int bm = blockIdx.x >> 6;   // 12
  int bn = blockIdx.x & 63;   // 64
  int wave = threadIdx.x >> 6, lane = threadIdx.x & 63;
  int r = lane & 15, g = lane >> 4;
  int m_row = bm * 64 + wave * 16 + r;
  int n0 = bn * 64;
  f32x4 acc[4] = {};
  for (int kk = 0; kk < NC; kk += 32) {
    f16x8 a = *(const f16x8*)&w[m_row * NC + kk + g * 8];
#pragma unroll
    for (int nt = 0; nt < 4; nt++) {
      f16x8 b = *(const f16x8*)&xt[(n0 + nt * 16 + r) * NC + kk + g * 8];
      acc[nt] = mfma16(a, b, acc[nt]);
    }
  }
  int mbase = bm * 64 + wave * 16 + g * 4;
  float bj[4];
#pragma unroll
  for (int j = 0; j < 4; j++) bj[j] = bias[mbase + j];
#pragma unroll
  for (int nt = 0; nt < 4; nt++)
#pragma unroll
    for (int j = 0; j < 4; j++)
      out[(mbase + j) * HW + n0 + nt * 16 + r] = acc[nt][j] + bj[j];
}

// ------------------- depthwise 11x11, pad 5, groups=768 --------------------
// q is pre-scaled by (1/temp)*log2(e) so softmax runs natively base-2.
__global__ __launch_bounds__(256) void k_dwconv(
    const float* __restrict__ qkv, const float* __restrict__ wdw,
    const float* __restrict__ bdw, f16* __restrict__ q_nm,
    f16* __restrict__ k_nm, f16* __restrict__ v_cm) {
  __shared__ float img[74 * 74];
  __shared__ float wgt[121];
  int c = blockIdx.x;
  int tid = threadIdx.x;
  for (int i = tid; i < 74 * 74; i += 256) {
    int row = i / 74, col = i - row * 74;
    int y = row - 5, xx = col - 5;
    img[i] = ((unsigned)y < 64u && (unsigned)xx < 64u) ? qkv[c * HW + y * 64 + xx]
                                                       : 0.f;
  }
  for (int i = tid; i < 121; i += 256) wgt[i] = wdw[c * 121 + i];
  __syncthreads();
  float bias = bdw[c];
#pragma unroll
  for (int it = 0; it < 2; it++) {
    int gi = it * 256 + tid;
    int px0 = gi * 8;
    int y = px0 >> 6, x0 = px0 & 63;
    float acc[8] = {};
#pragma unroll
    for (int ky = 0; ky < 11; ky++) {
      const float* rp = &img[(y + ky) * 74 + x0];
      float rv[18];
#pragma unroll
      for (int t = 0; t < 18; t++) rv[t] = rp[t];
#pragma unroll
      for (int kx = 0; kx < 11; kx++) {
        float wv = wgt[ky * 11 + kx];
#pragma unroll
        for (int p = 0; p < 8; p++) acc[p] = fmaf(rv[kx + p], wv, acc[p]);
      }
    }
    if (c < 256) {
      int h = c >> 5, d = c & 31;
#pragma unroll
      for (int p = 0; p < 8; p++)
        q_nm[(h * HW + px0 + p) * 32 + d] =
            (f16)((acc[p] + bias) * 0.28853900817779268f);  // 0.2*log2(e)
    } else if (c < 512) {
      int cc = c - 256;
      int h = cc >> 5, d = cc & 31;
#pragma unroll
      for (int p = 0; p < 8; p++)
        k_nm[(h * HW + px0 + p) * 32 + d] = (f16)(acc[p] + bias);
    } else {
      int cc = c - 512;
#pragma unroll
      for (int p = 0; p < 8; p++)
        v_cm[cc * HW + px0 + p] = (f16)(acc[p] + bias);
    }
  }
}

// ---------------- norms: ||q_row|| per row, max ||k_row|| per head ---------
__global__ __launch_bounds__(256) void k_norms(
    const f16* __restrict__ q_nm, const f16* __restrict__ k_nm,
    float* __restrict__ q_bound, int* __restrict__ kmax_bits) {
  __shared__ float red[256];
  int b = blockIdx.x, t = threadIdx.x;
  const f16* src = (b < 128) ? q_nm : k_nm;
  int row = ((b & 127) * 256) + t;
  const f16x8* p = (const f16x8*)&src[row * 32];
  float s = 0.f;
#pragma unroll
  for (int i = 0; i < 4; i++) {
    f16x8 v = p[i];
#pragma unroll
    for (int j = 0; j < 8; j++) {
      float f = (float)v[j];
      s = fmaf(f, f, s);
    }
  }
  float nrm = sqrtf(s);
  if (b < 128) {
    q_bound[row] = nrm;
  } else {
    red[t] = nrm;
    __syncthreads();
    for (int off = 128; off > 0; off >>= 1) {
      if (t < off) red[t] = fmaxf(red[t], red[t + off]);
      __syncthreads();
    }
    if (t == 0) atomicMax(&kmax_bits[row >> 12], __float_as_int(red[0]));
  }
}

// ----------------------------- flash attention -----------------------------
// Block = 512 threads = 8 waves = 32 q rows; wave w handles keys
// [w*512,(w+1)*512). Fixed-shift softmax: P = exp2(s - C_row), C_row =
// ||q_row||*maxk - 13.9 (Cauchy-Schwarz => P <= 2^13.9, f16-safe; the 2^C
// factor cancels in O/L). The -C shift rides in the score-MFMA C-operand.
// Main loop: no cross-lane ops, no branches, no subs. Partials summed across
// the 8 waves in LDS (same scale -> plain add).
// Scores transposed: S^T = mfma(A=K_tile row-permuted pr(i)=8*(i>>2)+(i&3),
// B=Q) so score C/D layout == PV A-fragment layout; P stays in registers.
// Block swizzle: h = bid&7 -> if dispatch round-robins XCDs, each XCD works
// one head and its 512KB K/V stays L2-resident.
__global__ __launch_bounds__(512, 8) void k_attn(
    const f16* __restrict__ q_nm, const f16* __restrict__ k_nm,
    const f16* __restrict__ v_cm, const float* __restrict__ q_bound,
    const int* __restrict__ kmax_bits, f16* __restrict__ newx) {
  __shared__ float s_acc[8][32][33];
  __shared__ float s_L[8][32];
  int h = blockIdx.x & 7;    // head-affine swizzle
  int qt = blockIdx.x >> 3;  // 128 q tiles of 32 rows
  int wave = threadIdx.x >> 6, lane = threadIdx.x & 63;
  int r = lane & 15, g = lane >> 4;
  int n_base = qt * 32;
  const f16* qh = q_nm + h * (HW * 32);
  const f16* kh = k_nm + h * (HW * 32);
  const f16* vh = v_cm + h * (32 * HW);

  f16x8 bq0 = *(const f16x8*)&qh[(n_base + r) * 32 + g * 8];
  f16x8 bq1 = *(const f16x8*)&qh[(n_base + 16 + r) * 32 + g * 8];
  float kmax = __int_as_float(kmax_bits[h]);
  float mCa = 13.9f - q_bound[h * HW + n_base + r] * kmax;
  float mCb = 13.9f - q_bound[h * HW + n_base + 16 + r] * kmax;
  f32x4 cinitA = {mCa, mCa, mCa, mCa};
  f32x4 cinitB = {mCb, mCb, mCb, mCb};

  int pr = ((r & 12) << 1) | (r & 3);  // 8*(r>>2)+(r&3)
  const f32x4 zero = {0.f, 0.f, 0.f, 0.f};
  f32x4 accA0 = zero, accA1 = zero, accB0 = zero, accB1 = zero;
  float La = 0.f, Lb = 0.f;

  int m_lo = wave << 9;  // 512 keys per wave
  const f16* kp = kh + (m_lo + pr) * 32 + g * 8;
  const f16* vp0 = vh + r * HW + m_lo + g * 8;
  const f16* vp1 = vp0 + 16 * HW;

  for (int it = 0; it < 16; ++it) {
    f16x8 ak0 = *(const f16x8*)(kp);
    f16x8 ak1 = *(const f16x8*)(kp + 128);
    f16x8 bv0 = *(const f16x8*)(vp0);
    f16x8 bv1 = *(const f16x8*)(vp1);
    kp += 1024;  // 32 keys * 32 d
    vp0 += 32;
    vp1 += 32;
    // scores (pre-shifted): sX[j] = S[key][q-row] - C_row
    f32x4 sA0 = mfma16(ak0, bq0, cinitA);
    f32x4 sA1 = mfma16(ak1, bq0, cinitA);
    f32x4 sB0 = mfma16(ak0, bq1, cinitB);
    f32x4 sB1 = mfma16(ak1, bq1, cinitB);
    float pA[8], pB[8];
#pragma unroll
    for (int j = 0; j < 4; j++) {
      pA[j] = EXP2(sA0[j]);
      pA[4 + j] = EXP2(sA1[j]);
      pB[j] = EXP2(sB0[j]);
      pB[4 + j] = EXP2(sB1[j]);
    }
    La += ((pA[0] + pA[1]) + (pA[2] + pA[3])) +
          ((pA[4] + pA[5]) + (pA[6] + pA[7]));
    Lb += ((pB[0] + pB[1]) + (pB[2] + pB[3])) +
          ((pB[4] + pB[5]) + (pB[6] + pB[7]));
    union { hf16x2 h2[4]; f16x8 v; } uA, uB;
#pragma unroll
    for (int j = 0; j < 4; j++) {
      uA.h2[j] = __builtin_amdgcn_cvt_pkrtz(pA[2 * j], pA[2 * j + 1]);
      uB.h2[j] = __builtin_amdgcn_cvt_pkrtz(pB[2 * j], pB[2 * j + 1]);
    }
    accA0 = mfma16(uA.v, bv0, accA0);
    accA1 = mfma16(uA.v, bv1, accA1);
    accB0 = mfma16(uB.v, bv0, accB0);
    accB1 = mfma16(uB.v, bv1, accB1);
  }
  // ---- per-wave partials -> LDS (all on the same fixed scale) ----
  La += __shfl_xor(La, 16);
  La += __shfl_xor(La, 32);
  Lb += __shfl_xor(Lb, 16);
  Lb += __shfl_xor(Lb, 32);
#pragma unroll
  for (int j = 0; j < 4; j++) {
    s_acc[wave][4 * g + j][r] = accA0[j];
    s_acc[wave][4 * g + j][16 + r] = accA1[j];
    s_acc[wave][16 + 4 * g + j][r] = accB0[j];
    s_acc[wave][16 + 4 * g + j][16 + r] = accB1[j];
  }
  if (lane < 16) {
    s_L[wave][r] = La;
    s_L[wave][16 + r] = Lb;
  }
  __syncthreads();
  // ---- combine the 8 key-eighths: plain sums, then O/L ----
  for (int idx = threadIdx.x; idx < 1024; idx += 512) {
    int row = idx >> 5, d = idx & 31;
    float O = ((s_acc[0][row][d] + s_acc[1][row][d]) +
               (s_acc[2][row][d] + s_acc[3][row][d])) +
              ((s_acc[4][row][d] + s_acc[5][row][d]) +
               (s_acc[6][row][d] + s_acc[7][row][d]));
    float L = ((s_L[0][row] + s_L[1][row]) + (s_L[2][row] + s_L[3][row])) +
              ((s_L[4][row] + s_L[5][row]) + (s_L[6][row] + s_L[7][row]));
    newx[(n_base + row) * NC + h * 32 + d] = (f16)(O / L);
  }
}

// ---------- GEMM2: out = relu(Wlin[256,256] * newx + b) + x ----------------
__global__ __launch_bounds__(256) void k_gemm_proj(
    const f16* __restrict__ w, const f16* __restrict__ nx,
    const float* __restrict__ bias, const float* __restrict__ x,
    float* __restrict__ out) {
  int bm = blockIdx.x >> 6;  // 4
  int bn = blockIdx.x & 63;  // 64
  int wave = threadIdx.x >> 6, lane = threadIdx.x & 63;
  int r = lane & 15, g = lane >> 4;
  int m_row = bm * 64 + wave * 16 + r;
  int n0 = bn * 64;
  f32x4 acc[4] = {};
  for (int kk = 0; kk < NC; kk += 32) {
    f16x8 a = *(const f16x8*)&w[m_row * NC + kk + g * 8];
#pragma unroll
    for (int nt = 0; nt < 4; nt++) {
      f16x8 b = *(const f16x8*)&nx[(n0 + nt * 16 + r) * NC + kk + g * 8];
      acc[nt] = mfma16(a, b, acc[nt]);
    }
  }
  int mbase = bm * 64 + wave * 16 + g * 4;
  float bj[4];
#pragma unroll
  for (int j = 0; j < 4; j++) bj[j] = bias[mbase + j];
#pragma unroll
  for (int nt = 0; nt < 4; nt++)
#pragma unroll
    for (int j = 0; j < 4; j++) {
      int m = mbase + j, n = n0 + nt * 16 + r;
      float v = fmaxf(acc[nt][j] + bj[j], 0.f) + x[m * HW + n];
      out[m * HW + n] = v;
    }
}

// ---------------------------------------------------------------------------
extern "C" void kernel_launch(void* const* d_in, const int* in_sizes, int n_in,
                              void* d_out, int out_size, void* d_ws,
                              size_t ws_size, hipStream_t stream) {
  const float* x = (const float*)d_in[0];
  const float* w_pw = (const float*)d_in[1];
  const float* b_pw = (const float*)d_in[2];
  const float* w_dw = (const float*)d_in[3];
  const float* b_dw = (const float*)d_in[4];
  const float* w_lin = (const float*)d_in[5];
  const float* b_lin = (const float*)d_in[6];
  float* out = (float*)d_out;

  char* ws = (char*)d_ws;
  f16* wpw_h = (f16*)(ws + 0);            // 768*256*2      = 393216
  f16* wlin_h = (f16*)(ws + 393216);      // 256*256*2      = 131072
  f16* xt = (f16*)(ws + 524288);          // 4096*256*2     = 2097152
  float* qkv = (float*)(ws + 2621440);    // 768*4096*4     = 12582912
  f16* q_nm = (f16*)(ws + 15204352);      // 8*4096*32*2    = 2097152
  f16* k_nm = (f16*)(ws + 17301504);      // 2097152
  f16* v_cm = (f16*)(ws + 19398656);      // 2097152
  f16* nx = (f16*)(ws + 21495808);        // 2097152
  float* q_bound = (float*)(ws + 23592960);  // 8*4096*4    = 131072
  int* kmax_bits = (int*)(ws + 23724032);    // 32 -> total 23724064 bytes

  k_prep_w<<<512, 256, 0, stream>>>(w_pw, w_lin, wpw_h, wlin_h, kmax_bits);
  k_transpose_x<<<1024, 256, 0, stream>>>(x, xt);
  k_gemm_qkv<<<768, 256, 0, stream>>>(wpw_h, xt, b_pw, qkv);
  k_dwconv<<<768, 256, 0, stream>>>(qkv, w_dw, b_dw, q_nm, k_nm, v_cm);
  k_norms<<<256, 256, 0, stream>>>(q_nm, k_nm, q_bound, kmax_bits);
  k_attn<<<1024, 512, 0, stream>>>(q_nm, k_nm, v_cm, q_bound, kmax_bits, nx);
  k_gemm_proj<<<256, 256, 0, stream>>>(wlin_h, nx, b_lin, x, out);
}

// Round 6
// 158.345 us; speedup vs baseline: 1.2755x; 1.2755x over previous
//
#include <hip/hip_runtime.h>

// ---------------------------------------------------------------------------
// attention_76089640615954 on MI355X (gfx950)
// x:[1,256,64,64] -> 1x1 conv (3C) -> 11x11 depthwise -> 8-head attn (N=4096,
// d=32, temp=5) -> 1x1 conv + bias -> relu + residual.
// fp16 MFMA (16x16x32) for GEMM-shaped work, fp32 accumulate.
// R3: fixed-shift softmax (Cauchy-Schwarz bound): 53.6us, latency-bound at
//     34% occupancy (grid-capped, 4 waves/block).
// R5: 512thr/8-wave blocks with 32 q-rows PER WAVE spilled (launch_bounds
//     (512,8) caps 64 VGPR vs ~90 live) -> WRITE_SIZE 2MB->302MB, 151us.
// R6: same 8-wave block, but wave state halved back to the R2 shape that
//     fit <=64 VGPRs: 8 waves = 2 q-groups x 4 key-quarters, each wave
//     16 q-rows x 1024 keys. LDS 17.4KB. Occupancy target 32 waves/CU.
// ---------------------------------------------------------------------------

typedef _Float16 f16;
typedef __fp16 hf16x2 __attribute__((ext_vector_type(2)));
typedef _Float16 f16x8 __attribute__((ext_vector_type(8)));
typedef float f32x4 __attribute__((ext_vector_type(4)));

#define HW 4096      // 64*64 pixels
#define NC 256       // channels

#if __has_builtin(__builtin_amdgcn_exp2f)
#define EXP2(x) __builtin_amdgcn_exp2f(x)
#else
#define EXP2(x) exp2f(x)
#endif

static __device__ __forceinline__ f32x4 mfma16(f16x8 a, f16x8 b, f32x4 c) {
  return __builtin_amdgcn_mfma_f32_16x16x32_f16(a, b, c, 0, 0, 0);
}

// --------------------------- prep: weights -> fp16 -------------------------
__global__ __launch_bounds__(256) void k_prep_w(
    const float* __restrict__ wpw, const float* __restrict__ wlin,
    f16* __restrict__ wpw_h, f16* __restrict__ wlin_h,
    int* __restrict__ kmax_bits) {
  int i = blockIdx.x * 256 + threadIdx.x;
  if (i < 8) kmax_bits[i] = 0;  // init for k_norms' atomicMax
  int stride = gridDim.x * 256;
  for (int idx = i; idx < 3 * NC * NC; idx += stride) wpw_h[idx] = (f16)wpw[idx];
  for (int idx = i; idx < NC * NC; idx += stride) wlin_h[idx] = (f16)wlin[idx];
}

// --------------------------- prep: x -> xt[p][c] fp16 ----------------------
__global__ __launch_bounds__(256) void k_transpose_x(
    const float* __restrict__ x, f16* __restrict__ xt) {
  __shared__ float t[32][33];
  int bc = blockIdx.x >> 7;    // 8 channel tiles of 32
  int bp = blockIdx.x & 127;   // 128 pixel tiles of 32
  int tx = threadIdx.x & 31, ty = threadIdx.x >> 5;  // ty 0..7
#pragma unroll
  for (int i = 0; i < 4; i++) {
    int c = bc * 32 + ty + i * 8;
    t[ty + i * 8][tx] = x[c * HW + bp * 32 + tx];
  }
  __syncthreads();
#pragma unroll
  for (int i = 0; i < 4; i++) {
    int p = bp * 32 + ty + i * 8;
    xt[p * NC + bc * 32 + tx] = (f16)t[tx][ty + i * 8];
  }
}

// ------------------- GEMM1: qkv = Wpw[768,256] * x  (+bias) ----------------
__global__ __launch_bounds__(256) void k_gemm_qkv(
    const f16* __restrict__ w, const f16* __restrict__ xt,
    const float* __restrict__ bias, float* __restrict__ out) {
  int bm = blockIdx.x >> 6;   // 12
  int bn = blockIdx.x & 63;   // 64
  int wave = threadIdx.x >> 6, lane = threadIdx.x & 63;
  int r = lane & 15, g = lane >> 4;
  int m_row = bm * 64 + wave * 16 + r;
  int n0 = bn * 64;
  f32x4 acc[4] = {};
  for (int kk = 0; kk < NC; kk += 32) {
    f16x8 a = *(const f16x8*)&w[m_row * NC + kk + g * 8];
#pragma unroll
    for (int nt = 0; nt < 4; nt++) {
      f16x8 b = *(const f16x8*)&xt[(n0 + nt * 16 + r) * NC + kk + g * 8];
      acc[nt] = mfma16(a, b, acc[nt]);
    }
  }
  int mbase = bm * 64 + wave * 16 + g * 4;
  float bj[4];
#pragma unroll
  for (int j = 0; j < 4; j++) bj[j] = bias[mbase + j];
#pragma unroll
  for (int nt = 0; nt < 4; nt++)
#pragma unroll
    for (int j = 0; j < 4; j++)
      out[(mbase + j) * HW + n0 + nt * 16 + r] = acc[nt][j] + bj[j];
}

// ------------------- depthwise 11x11, pad 5, groups=768 --------------------
// q is pre-scaled by (1/temp)*log2(e) so softmax runs natively base-2.
__global__ __launch_bounds__(256) void k_dwconv(
    const float* __restrict__ qkv, const float* __restrict__ wdw,
    const float* __restrict__ bdw, f16* __restrict__ q_nm,
    f16* __restrict__ k_nm, f16* __restrict__ v_cm) {
  __shared__ float img[74 * 74];
  __shared__ float wgt[121];
  int c = blockIdx.x;
  int tid = threadIdx.x;
  for (int i = tid; i < 74 * 74; i += 256) {
    int row = i / 74, col = i - row * 74;
    int y = row - 5, xx = col - 5;
    img[i] = ((unsigned)y < 64u && (unsigned)xx < 64u) ? qkv[c * HW + y * 64 + xx]
                                                       : 0.f;
  }
  for (int i = tid; i < 121; i += 256) wgt[i] = wdw[c * 121 + i];
  __syncthreads();
  float bias = bdw[c];
#pragma unroll
  for (int it = 0; it < 2; it++) {
    int gi = it * 256 + tid;
    int px0 = gi * 8;
    int y = px0 >> 6, x0 = px0 & 63;
    float acc[8] = {};
#pragma unroll
    for (int ky = 0; ky < 11; ky++) {
      const float* rp = &img[(y + ky) * 74 + x0];
      float rv[18];
#pragma unroll
      for (int t = 0; t < 18; t++) rv[t] = rp[t];
#pragma unroll
      for (int kx = 0; kx < 11; kx++) {
        float wv = wgt[ky * 11 + kx];
#pragma unroll
        for (int p = 0; p < 8; p++) acc[p] = fmaf(rv[kx + p], wv, acc[p]);
      }
    }
    if (c < 256) {
      int h = c >> 5, d = c & 31;
#pragma unroll
      for (int p = 0; p < 8; p++)
        q_nm[(h * HW + px0 + p) * 32 + d] =
            (f16)((acc[p] + bias) * 0.28853900817779268f);  // 0.2*log2(e)
    } else if (c < 512) {
      int cc = c - 256;
      int h = cc >> 5, d = cc & 31;
#pragma unroll
      for (int p = 0; p < 8; p++)
        k_nm[(h * HW + px0 + p) * 32 + d] = (f16)(acc[p] + bias);
    } else {
      int cc = c - 512;
#pragma unroll
      for (int p = 0; p < 8; p++)
        v_cm[cc * HW + px0 + p] = (f16)(acc[p] + bias);
    }
  }
}

// ---------------- norms: ||q_row|| per row, max ||k_row|| per head ---------
__global__ __launch_bounds__(256) void k_norms(
    const f16* __restrict__ q_nm, const f16* __restrict__ k_nm,
    float* __restrict__ q_bound, int* __restrict__ kmax_bits) {
  __shared__ float red[256];
  int b = blockIdx.x, t = threadIdx.x;
  const f16* src = (b < 128) ? q_nm : k_nm;
  int row = ((b & 127) * 256) + t;
  const f16x8* p = (const f16x8*)&src[row * 32];
  float s = 0.f;
#pragma unroll
  for (int i = 0; i < 4; i++) {
    f16x8 v = p[i];
#pragma unroll
    for (int j = 0; j < 8; j++) {
      float f = (float)v[j];
      s = fmaf(f, f, s);
    }
  }
  float nrm = sqrtf(s);
  if (b < 128) {
    q_bound[row] = nrm;
  } else {
    red[t] = nrm;
    __syncthreads();
    for (int off = 128; off > 0; off >>= 1) {
      if (t < off) red[t] = fmaxf(red[t], red[t + off]);
      __syncthreads();
    }
    if (t == 0) atomicMax(&kmax_bits[row >> 12], __float_as_int(red[0]));
  }
}

// ----------------------------- flash attention -----------------------------
// Block = 512 threads = 8 waves = 2 q-groups x 4 key-quarters; block covers
// 32 q rows. Wave (qg,kq) handles q rows [n_base+qg*16, +16) x keys
// [kq*1024,(kq+1)*1024). Per-wave register state = R2 shape (<=64 VGPRs).
// Fixed-shift softmax: P = exp2(s - C_row), C_row = ||q_row||*maxk - 13.9
// (Cauchy-Schwarz => P <= 2^13.9, f16-safe; 2^C cancels in O/L); shift rides
// in the score-MFMA C-operand. Main loop: no cross-lane ops, no branches.
// Scores transposed: S^T = mfma(A=K_tile row-permuted pr(i)=8*(i>>2)+(i&3),
// B=Q) so score C/D layout == PV A-fragment layout; P stays in registers.
// Partials summed across the 4 key-quarter waves in LDS (same fixed scale).
// Block swizzle: h = bid&7 -> each XCD works one head, K/V L2-resident.
__global__ __launch_bounds__(512, 8) void k_attn(
    const f16* __restrict__ q_nm, const f16* __restrict__ k_nm,
    const f16* __restrict__ v_cm, const float* __restrict__ q_bound,
    const int* __restrict__ kmax_bits, f16* __restrict__ newx) {
  __shared__ float s_acc[8][16][33];
  __shared__ float s_L[8][16];
  int h = blockIdx.x & 7;    // head-affine swizzle
  int qt = blockIdx.x >> 3;  // 128 q tiles of 32 rows
  int wave = threadIdx.x >> 6, lane = threadIdx.x & 63;
  int qg = wave >> 2, kq = wave & 3;
  int r = lane & 15, g = lane >> 4;
  int n_base = qt * 32 + qg * 16;
  const f16* qh = q_nm + h * (HW * 32);
  const f16* kh = k_nm + h * (HW * 32);
  const f16* vh = v_cm + h * (32 * HW);

  f16x8 bq = *(const f16x8*)&qh[(n_base + r) * 32 + g * 8];
  float kmax = __int_as_float(kmax_bits[h]);
  float mC = 13.9f - q_bound[h * HW + n_base + r] * kmax;
  f32x4 cinit = {mC, mC, mC, mC};

  int pr = ((r & 12) << 1) | (r & 3);  // 8*(r>>2)+(r&3)
  const f32x4 zero = {0.f, 0.f, 0.f, 0.f};
  f32x4 acc0 = zero, acc1 = zero;
  float L = 0.f;

  int m_lo = kq << 10;  // 1024 keys per wave
  const f16* kp = kh + (m_lo + pr) * 32 + g * 8;
  const f16* vp0 = vh + r * HW + m_lo + g * 8;
  const f16* vp1 = vp0 + 16 * HW;

  for (int it = 0; it < 32; ++it) {
    f16x8 ak0 = *(const f16x8*)(kp);
    f16x8 ak1 = *(const f16x8*)(kp + 128);
    f16x8 bv0 = *(const f16x8*)(vp0);
    f16x8 bv1 = *(const f16x8*)(vp1);
    kp += 1024;  // 32 keys * 32 d
    vp0 += 32;
    vp1 += 32;
    // scores (pre-shifted): s[j] = S[key m_lo+32it+8g+j(+4)][row n_base+r] - C
    f32x4 s0 = mfma16(ak0, bq, cinit);
    f32x4 s1 = mfma16(ak1, bq, cinit);
    float p[8];
#pragma unroll
    for (int j = 0; j < 4; j++) {
      p[j] = EXP2(s0[j]);
      p[4 + j] = EXP2(s1[j]);
    }
    L += ((p[0] + p[1]) + (p[2] + p[3])) + ((p[4] + p[5]) + (p[6] + p[7]));
    union { hf16x2 h2[4]; f16x8 v; } u;
#pragma unroll
    for (int j = 0; j < 4; j++)
      u.h2[j] = __builtin_amdgcn_cvt_pkrtz(p[2 * j], p[2 * j + 1]);
    acc0 = mfma16(u.v, bv0, acc0);
    acc1 = mfma16(u.v, bv1, acc1);
  }
  // ---- per-wave partials -> LDS (all on the same fixed scale) ----
  L += __shfl_xor(L, 16);
  L += __shfl_xor(L, 32);
#pragma unroll
  for (int j = 0; j < 4; j++) {
    s_acc[wave][4 * g + j][r] = acc0[j];       // O[row 4g+j][d=r]
    s_acc[wave][4 * g + j][16 + r] = acc1[j];  // O[row 4g+j][d=16+r]
  }
  if (lane < 16) s_L[wave][r] = L;
  __syncthreads();
  // ---- combine the 4 key-quarters per q-group: plain sums, then O/L ----
  for (int idx = threadIdx.x; idx < 1024; idx += 512) {
    int row = idx >> 5, d = idx & 31;  // row 0..31 within the 32-row tile
    int w0 = (row >> 4) * 4, rr = row & 15;
    float O = (s_acc[w0 + 0][rr][d] + s_acc[w0 + 1][rr][d]) +
              (s_acc[w0 + 2][rr][d] + s_acc[w0 + 3][rr][d]);
    float Ls = (s_L[w0 + 0][rr] + s_L[w0 + 1][rr]) +
               (s_L[w0 + 2][rr] + s_L[w0 + 3][rr]);
    newx[(qt * 32 + row) * NC + h * 32 + d] = (f16)(O / Ls);
  }
}

// ---------- GEMM2: out = relu(Wlin[256,256] * newx + b) + x ----------------
__global__ __launch_bounds__(256) void k_gemm_proj(
    const f16* __restrict__ w, const f16* __restrict__ nx,
    const float* __restrict__ bias, const float* __restrict__ x,
    float* __restrict__ out) {
  int bm = blockIdx.x >> 6;  // 4
  int bn = blockIdx.x & 63;  // 64
  int wave = threadIdx.x >> 6, lane = threadIdx.x & 63;
  int r = lane & 15, g = lane >> 4;
  int m_row = bm * 64 + wave * 16 + r;
  int n0 = bn * 64;
  f32x4 acc[4] = {};
  for (int kk = 0; kk < NC; kk += 32) {
    f16x8 a = *(const f16x8*)&w[m_row * NC + kk + g * 8];
#pragma unroll
    for (int nt = 0; nt < 4; nt++) {
      f16x8 b = *(const f16x8*)&nx[(n0 + nt * 16 + r) * NC + kk + g * 8];
      acc[nt] = mfma16(a, b, acc[nt]);
    }
  }
  int mbase = bm * 64 + wave * 16 + g * 4;
  float bj[4];
#pragma unroll
  for (int j = 0; j < 4; j++) bj[j] = bias[mbase + j];
#pragma unroll
  for (int nt = 0; nt < 4; nt++)
#pragma unroll
    for (int j = 0; j < 4; j++) {
      int m = mbase + j, n = n0 + nt * 16 + r;
      float v = fmaxf(acc[nt][j] + bj[j], 0.f) + x[m * HW + n];
      out[m * HW + n] = v;
    }
}

// ---------------------------------------------------------------------------
extern "C" void kernel_launch(void* const* d_in, const int* in_sizes, int n_in,
                              void* d_out, int out_size, void* d_ws,
                              size_t ws_size, hipStream_t stream) {
  const float* x = (const float*)d_in[0];
  const float* w_pw = (const float*)d_in[1];
  const float* b_pw = (const float*)d_in[2];
  const float* w_dw = (const float*)d_in[3];
  const float* b_dw = (const float*)d_in[4];
  const float* w_lin = (const float*)d_in[5];
  const float* b_lin = (const float*)d_in[6];
  float* out = (float*)d_out;

  char* ws = (char*)d_ws;
  f16* wpw_h = (f16*)(ws + 0);            // 768*256*2      = 393216
  f16* wlin_h = (f16*)(ws + 393216);      // 256*256*2      = 131072
  f16* xt = (f16*)(ws + 524288);          // 4096*256*2     = 2097152
  float* qkv = (float*)(ws + 2621440);    // 768*4096*4     = 12582912
  f16* q_nm = (f16*)(ws + 15204352);      // 8*4096*32*2    = 2097152
  f16* k_nm = (f16*)(ws + 17301504);      // 2097152
  f16* v_cm = (f16*)(ws + 19398656);      // 2097152
  f16* nx = (f16*)(ws + 21495808);        // 2097152
  float* q_bound = (float*)(ws + 23592960);  // 8*4096*4    = 131072
  int* kmax_bits = (int*)(ws + 23724032);    // 32 -> total 23724064 bytes

  k_prep_w<<<512, 256, 0, stream>>>(w_pw, w_lin, wpw_h, wlin_h, kmax_bits);
  k_transpose_x<<<1024, 256, 0, stream>>>(x, xt);
  k_gemm_qkv<<<768, 256, 0, stream>>>(wpw_h, xt, b_pw, qkv);
  k_dwconv<<<768, 256, 0, stream>>>(qkv, w_dw, b_dw, q_nm, k_nm, v_cm);
  k_norms<<<256, 256, 0, stream>>>(q_nm, k_nm, q_bound, kmax_bits);
  k_attn<<<1024, 512, 0, stream>>>(q_nm, k_nm, v_cm, q_bound, kmax_bits, nx);
  k_gemm_proj<<<256, 256, 0, stream>>>(wlin_h, nx, b_lin, x, out);
}

// Round 7
// 103.739 us; speedup vs baseline: 1.9469x; 1.5264x over previous
//
#include <hip/hip_runtime.h>

// ---------------------------------------------------------------------------
// attention_76089640615954 on MI355X (gfx950)
// x:[1,256,64,64] -> 1x1 conv (3C) -> 11x11 depthwise -> 8-head attn (N=4096,
// d=32, temp=5) -> 1x1 conv + bias -> relu + residual.
// fp16 MFMA (16x16x32), fp32 accumulate, fixed-shift softmax (Cauchy-Schwarz
// bound precomputed by k_norms; exp2 shift rides in the score-MFMA C-operand).
// R6 evidence: dur tracks K/V cache traffic (R3 512MB/53.6us, R6 1GB/94.8us,
// both ~10TB/s effective on per-lane gather loads; VALU 15%, MFMA 7%, HBM 0%)
// => bound by L2 re-streaming, not VALU/latency/occupancy.
// R7: 128-row q-tile per block (8 waves x 16 rows) + LDS-staged K/V via
// global_load_lds(16B) double-buffered 64-key chunks => traffic 1GB -> 128MB.
// V stored d-major with XOR swizzle (linear LDS dest + inverse-swizzled
// global source + XOR on read). 2-way key split across blocks (grid 512,
// 2 blocks/CU); partial O/L combined by k_norm_o (partials alias dead qkv).
// ---------------------------------------------------------------------------

typedef _Float16 f16;
typedef __fp16 hf16x2 __attribute__((ext_vector_type(2)));
typedef _Float16 f16x4 __attribute__((ext_vector_type(4)));
typedef _Float16 f16x8 __attribute__((ext_vector_type(8)));
typedef float f32x4 __attribute__((ext_vector_type(4)));

#define HW 4096      // 64*64 pixels
#define NC 256       // channels
#define CHUNK 64     // keys staged per iteration
#define NIT 32       // 2048 keys per block / CHUNK

#if __has_builtin(__builtin_amdgcn_exp2f)
#define EXP2(x) __builtin_amdgcn_exp2f(x)
#else
#define EXP2(x) exp2f(x)
#endif

static __device__ __forceinline__ f32x4 mfma16(f16x8 a, f16x8 b, f32x4 c) {
  return __builtin_amdgcn_mfma_f32_16x16x32_f16(a, b, c, 0, 0, 0);
}

static __device__ __forceinline__ void gload16(const void* g, void* l) {
  __builtin_amdgcn_global_load_lds(
      (const __attribute__((address_space(1))) unsigned int*)g,
      (__attribute__((address_space(3))) unsigned int*)l, 16, 0, 0);
}

// --------------------------- prep: weights -> fp16 -------------------------
__global__ __launch_bounds__(256) void k_prep_w(
    const float* __restrict__ wpw, const float* __restrict__ wlin,
    f16* __restrict__ wpw_h, f16* __restrict__ wlin_h,
    int* __restrict__ kmax_bits) {
  int i = blockIdx.x * 256 + threadIdx.x;
  if (i < 8) kmax_bits[i] = 0;  // init for k_norms' atomicMax
  int stride = gridDim.x * 256;
  for (int idx = i; idx < 3 * NC * NC; idx += stride) wpw_h[idx] = (f16)wpw[idx];
  for (int idx = i; idx < NC * NC; idx += stride) wlin_h[idx] = (f16)wlin[idx];
}

// --------------------------- prep: x -> xt[p][c] fp16 ----------------------
__global__ __launch_bounds__(256) void k_transpose_x(
    const float* __restrict__ x, f16* __restrict__ xt) {
  __shared__ float t[32][33];
  int bc = blockIdx.x >> 7;    // 8 channel tiles of 32
  int bp = blockIdx.x & 127;   // 128 pixel tiles of 32
  int tx = threadIdx.x & 31, ty = threadIdx.x >> 5;  // ty 0..7
#pragma unroll
  for (int i = 0; i < 4; i++) {
    int c = bc * 32 + ty + i * 8;
    t[ty + i * 8][tx] = x[c * HW + bp * 32 + tx];
  }
  __syncthreads();
#pragma unroll
  for (int i = 0; i < 4; i++) {
    int p = bp * 32 + ty + i * 8;
    xt[p * NC + bc * 32 + tx] = (f16)t[tx][ty + i * 8];
  }
}

// ------------------- GEMM1: qkv = Wpw[768,256] * x  (+bias) ----------------
__global__ __launch_bounds__(256) void k_gemm_qkv(
    const f16* __restrict__ w, const f16* __restrict__ xt,
    const float* __restrict__ bias, float* __restrict__ out) {
  int bm = blockIdx.x >> 6;   // 12
  int bn = blockIdx.x & 63;   // 64
  int wave = threadIdx.x >> 6, lane = threadIdx.x & 63;
  int r = lane & 15, g = lane >> 4;
  int m_row = bm * 64 + wave * 16 + r;
  int n0 = bn * 64;
  f32x4 acc[4] = {};
  for (int kk = 0; kk < NC; kk += 32) {
    f16x8 a = *(const f16x8*)&w[m_row * NC + kk + g * 8];
#pragma unroll
    for (int nt = 0; nt < 4; nt++) {
      f16x8 b = *(const f16x8*)&xt[(n0 + nt * 16 + r) * NC + kk + g * 8];
      acc[nt] = mfma16(a, b, acc[nt]);
    }
  }
  int mbase = bm * 64 + wave * 16 + g * 4;
  float bj[4];
#pragma unroll
  for (int j = 0; j < 4; j++) bj[j] = bias[mbase + j];
#pragma unroll
  for (int nt = 0; nt < 4; nt++)
#pragma unroll
    for (int j = 0; j < 4; j++)
      out[(mbase + j) * HW + n0 + nt * 16 + r] = acc[nt][j] + bj[j];
}

// ------------------- depthwise 11x11, pad 5, groups=768 --------------------
// q is pre-scaled by (1/temp)*log2(e) so softmax runs natively base-2.
__global__ __launch_bounds__(256) void k_dwconv(
    const float* __restrict__ qkv, const float* __restrict__ wdw,
    const float* __restrict__ bdw, f16* __restrict__ q_nm,
    f16* __restrict__ k_nm, f16* __restrict__ v_cm) {
  __shared__ float img[74 * 74];
  __shared__ float wgt[121];
  int c = blockIdx.x;
  int tid = threadIdx.x;
  for (int i = tid; i < 74 * 74; i += 256) {
    int row = i / 74, col = i - row * 74;
    int y = row - 5, xx = col - 5;
    img[i] = ((unsigned)y < 64u && (unsigned)xx < 64u) ? qkv[c * HW + y * 64 + xx]
                                                       : 0.f;
  }
  for (int i = tid; i < 121; i += 256) wgt[i] = wdw[c * 121 + i];
  __syncthreads();
  float bias = bdw[c];
#pragma unroll
  for (int it = 0; it < 2; it++) {
    int gi = it * 256 + tid;
    int px0 = gi * 8;
    int y = px0 >> 6, x0 = px0 & 63;
    float acc[8] = {};
#pragma unroll
    for (int ky = 0; ky < 11; ky++) {
      const float* rp = &img[(y + ky) * 74 + x0];
      float rv[18];
#pragma unroll
      for (int t = 0; t < 18; t++) rv[t] = rp[t];
#pragma unroll
      for (int kx = 0; kx < 11; kx++) {
        float wv = wgt[ky * 11 + kx];
#pragma unroll
        for (int p = 0; p < 8; p++) acc[p] = fmaf(rv[kx + p], wv, acc[p]);
      }
    }
    if (c < 256) {
      int h = c >> 5, d = c & 31;
#pragma unroll
      for (int p = 0; p < 8; p++)
        q_nm[(h * HW + px0 + p) * 32 + d] =
            (f16)((acc[p] + bias) * 0.28853900817779268f);  // 0.2*log2(e)
    } else if (c < 512) {
      int cc = c - 256;
      int h = cc >> 5, d = cc & 31;
#pragma unroll
      for (int p = 0; p < 8; p++)
        k_nm[(h * HW + px0 + p) * 32 + d] = (f16)(acc[p] + bias);
    } else {
      int cc = c - 512;
#pragma unroll
      for (int p = 0; p < 8; p++)
        v_cm[cc * HW + px0 + p] = (f16)(acc[p] + bias);
    }
  }
}

// ---------------- norms: ||q_row|| per row, max ||k_row|| per head ---------
__global__ __launch_bounds__(256) void k_norms(
    const f16* __restrict__ q_nm, const f16* __restrict__ k_nm,
    float* __restrict__ q_bound, int* __restrict__ kmax_bits) {
  __shared__ float red[256];
  int b = blockIdx.x, t = threadIdx.x;
  const f16* src = (b < 128) ? q_nm : k_nm;
  int row = ((b & 127) * 256) + t;
  const f16x8* p = (const f16x8*)&src[row * 32];
  float s = 0.f;
#pragma unroll
  for (int i = 0; i < 4; i++) {
    f16x8 v = p[i];
#pragma unroll
    for (int j = 0; j < 8; j++) {
      float f = (float)v[j];
      s = fmaf(f, f, s);
    }
  }
  float nrm = sqrtf(s);
  if (b < 128) {
    q_bound[row] = nrm;
  } else {
    red[t] = nrm;
    __syncthreads();
    for (int off = 128; off > 0; off >>= 1) {
      if (t < off) red[t] = fmaxf(red[t], red[t + off]);
      __syncthreads();
    }
    if (t == 0) atomicMax(&kmax_bits[row >> 12], __float_as_int(red[0]));
  }
}

// ----------------------------- flash attention -----------------------------
// Block = 512 threads = 8 waves; q-tile = 128 rows (wave wv owns rows
// [qt*128+wv*16, +16)); block handles key-half kg (2048 keys) in 32 LDS-staged
// 64-key chunks (double-buffered). Waves 0-3 stage K, 4-7 stage V, all 8
// consume. K LDS layout: [key][d] linear (global_load_lds-direct). V LDS
// layout: [d][key] with XOR swizzle byte^=((d&7)<<4): linear LDS dest +
// inverse-swizzled global src + XOR on read (kills 16-way bank conflict).
// Fixed-shift softmax: P = exp2(s - C_row) with C in the MFMA C-operand;
// partial O (fp32) and L per key-half written to workspace; k_norm_o combines.
__global__ __launch_bounds__(512, 4) void k_attn(
    const f16* __restrict__ q_nm, const f16* __restrict__ k_nm,
    const f16* __restrict__ v_cm, const float* __restrict__ q_bound,
    const int* __restrict__ kmax_bits, float* __restrict__ o_part,
    float* __restrict__ l_part) {
  __shared__ f16 lds_k[2][CHUNK * 32];
  __shared__ f16 lds_v[2][32 * CHUNK];
  int bid = blockIdx.x;
  int h = bid & 7, kg = (bid >> 3) & 1, qt = bid >> 4;
  int tid = threadIdx.x;
  int wv = tid >> 6, lane = tid & 63;
  int r = lane & 15, g = lane >> 4;
  int n_base = qt * 128 + wv * 16;
  const f16* qh = q_nm + h * (HW * 32);
  const f16* kh = k_nm + h * (HW * 32);
  const f16* vh = v_cm + h * (32 * HW);
  int m_lo = kg << 11;  // 2048 keys per block

  // staging sources (16B per thread per chunk)
  // K: waves 0-3: key = wv*16 + lane/4, d-offset = (lane&3)*8, linear dest
  const f16* kg_src =
      kh + (m_lo + (wv & 3) * 16 + (lane >> 2)) * 32 + (lane & 3) * 8;
  // V: waves 4-7: d = t2/8, key-block inverse-swizzled, linear dest
  int t2 = (tid >= 256) ? tid - 256 : 0;
  int vd = t2 >> 3;
  int vk = ((t2 & 7) ^ (vd & 7)) * 8;
  const f16* vg_src = vh + vd * HW + m_lo + vk;

#define STAGE(it, buf)                                                       \
  do {                                                                       \
    if (wv < 4)                                                              \
      gload16(kg_src + (it) * (CHUNK * 32), &lds_k[buf][(wv & 3) * 512]);    \
    else                                                                     \
      gload16(vg_src + (it) * CHUNK, &lds_v[buf][(wv - 4) * 512]);           \
  } while (0)

  f16x8 bq = *(const f16x8*)&qh[(n_base + r) * 32 + g * 8];
  float kmax = __int_as_float(kmax_bits[h]);
  float mC = 13.9f - q_bound[h * HW + n_base + r] * kmax;
  f32x4 cinit = {mC, mC, mC, mC};
  int pr = ((r & 12) << 1) | (r & 3);  // 8*(r>>2)+(r&3)
  f32x4 acc0 = {0.f, 0.f, 0.f, 0.f}, acc1 = {0.f, 0.f, 0.f, 0.f};
  float L = 0.f;

  STAGE(0, 0);
  for (int it = 0; it < NIT; ++it) {
    int buf = it & 1;
    if (it + 1 < NIT) STAGE(it + 1, buf ^ 1);
    __syncthreads();  // drains vmcnt -> staged chunk visible to all waves
    const f16* kb = &lds_k[buf][0];
    const char* vb = (const char*)&lds_v[buf][0];
#pragma unroll
    for (int ks = 0; ks < 2; ++ks) {
      f16x8 ak0 = *(const f16x8*)&kb[(ks * 32 + pr) * 32 + g * 8];
      f16x8 ak1 = *(const f16x8*)&kb[(ks * 32 + pr + 4) * 32 + g * 8];
      int vbyte = (r * 128 + ks * 64 + g * 16) ^ ((r & 7) << 4);
      f16x8 bv0 = *(const f16x8*)(vb + vbyte);          // V[d=r][...]
      f16x8 bv1 = *(const f16x8*)(vb + vbyte + 2048);   // V[d=16+r][...]
      f32x4 s0 = mfma16(ak0, bq, cinit);
      f32x4 s1 = mfma16(ak1, bq, cinit);
      float p[8];
#pragma unroll
      for (int j = 0; j < 4; j++) {
        p[j] = EXP2(s0[j]);
        p[4 + j] = EXP2(s1[j]);
      }
      L += ((p[0] + p[1]) + (p[2] + p[3])) + ((p[4] + p[5]) + (p[6] + p[7]));
      union { hf16x2 h2[4]; f16x8 v; } u;
#pragma unroll
      for (int j = 0; j < 4; j++)
        u.h2[j] = __builtin_amdgcn_cvt_pkrtz(p[2 * j], p[2 * j + 1]);
      acc0 = mfma16(u.v, bv0, acc0);
      acc1 = mfma16(u.v, bv1, acc1);
    }
    __syncthreads();  // all waves done reading buf before it's restaged
  }
  // ---- per-wave partials (fixed scale) -> workspace ----
  L += __shfl_xor(L, 16);
  L += __shfl_xor(L, 32);
  float* op = o_part + (((size_t)kg * 8 + h) * HW + n_base) * 32;
#pragma unroll
  for (int j = 0; j < 4; j++) {
    op[(4 * g + j) * 32 + r] = acc0[j];
    op[(4 * g + j) * 32 + 16 + r] = acc1[j];
  }
  if (lane < 16) l_part[((size_t)kg * 8 + h) * HW + n_base + r] = L;
#undef STAGE
}

// ---------------- combine key-halves and normalize -> nx f16 ---------------
__global__ __launch_bounds__(256) void k_norm_o(
    const float* __restrict__ o_part, const float* __restrict__ l_part,
    f16* __restrict__ nx) {
  int idx = blockIdx.x * 256 + threadIdx.x;  // 262144 threads, 4 elems each
  f32x4 o0 = *(const f32x4*)&o_part[(size_t)idx * 4];
  f32x4 o1 = *(const f32x4*)&o_part[(size_t)idx * 4 + 8 * HW * 32];
  float Ls = l_part[idx >> 3] + l_part[(idx >> 3) + 8 * HW];
  float inv = 1.f / Ls;
  int h = idx >> 15, row = (idx >> 3) & (HW - 1), d0 = (idx & 7) * 4;
  f16x4 out;
#pragma unroll
  for (int j = 0; j < 4; j++) out[j] = (f16)((o0[j] + o1[j]) * inv);
  *(f16x4*)&nx[row * NC + h * 32 + d0] = out;
}

// ---------- GEMM2: out = relu(Wlin[256,256] * newx + b) + x ----------------
__global__ __launch_bounds__(256) void k_gemm_proj(
    const f16* __restrict__ w, const f16* __restrict__ nx,
    const float* __restrict__ bias, const float* __restrict__ x,
    float* __restrict__ out) {
  int bm = blockIdx.x >> 6;  // 4
  int bn = blockIdx.x & 63;  // 64
  int wave = threadIdx.x >> 6, lane = threadIdx.x & 63;
  int r = lane & 15, g = lane >> 4;
  int m_row = bm * 64 + wave * 16 + r;
  int n0 = bn * 64;
  f32x4 acc[4] = {};
  for (int kk = 0; kk < NC; kk += 32) {
    f16x8 a = *(const f16x8*)&w[m_row * NC + kk + g * 8];
#pragma unroll
    for (int nt = 0; nt < 4; nt++) {
      f16x8 b = *(const f16x8*)&nx[(n0 + nt * 16 + r) * NC + kk + g * 8];
      acc[nt] = mfma16(a, b, acc[nt]);
    }
  }
  int mbase = bm * 64 + wave * 16 + g * 4;
  float bj[4];
#pragma unroll
  for (int j = 0; j < 4; j++) bj[j] = bias[mbase + j];
#pragma unroll
  for (int nt = 0; nt < 4; nt++)
#pragma unroll
    for (int j = 0; j < 4; j++) {
      int m = mbase + j, n = n0 + nt * 16 + r;
      float v = fmaxf(acc[nt][j] + bj[j], 0.f) + x[m * HW + n];
      out[m * HW + n] = v;
    }
}

// ---------------------------------------------------------------------------
extern "C" void kernel_launch(void* const* d_in, const int* in_sizes, int n_in,
                              void* d_out, int out_size, void* d_ws,
                              size_t ws_size, hipStream_t stream) {
  const float* x = (const float*)d_in[0];
  const float* w_pw = (const float*)d_in[1];
  const float* b_pw = (const float*)d_in[2];
  const float* w_dw = (const float*)d_in[3];
  const float* b_dw = (const float*)d_in[4];
  const float* w_lin = (const float*)d_in[5];
  const float* b_lin = (const float*)d_in[6];
  float* out = (float*)d_out;

  char* ws = (char*)d_ws;
  f16* wpw_h = (f16*)(ws + 0);            // 768*256*2      = 393216
  f16* wlin_h = (f16*)(ws + 393216);      // 256*256*2      = 131072
  f16* xt = (f16*)(ws + 524288);          // 4096*256*2     = 2097152
  float* qkv = (float*)(ws + 2621440);    // 768*4096*4     = 12582912
  f16* q_nm = (f16*)(ws + 15204352);      // 8*4096*32*2    = 2097152
  f16* k_nm = (f16*)(ws + 17301504);      // 2097152
  f16* v_cm = (f16*)(ws + 19398656);      // 2097152
  f16* nx = (f16*)(ws + 21495808);        // 2097152
  float* q_bound = (float*)(ws + 23592960);  // 8*4096*4    = 131072
  int* kmax_bits = (int*)(ws + 23724032);    // 32 -> total 23724064 bytes
  // o_part/l_part alias qkv (dead after k_dwconv): 8MB + 256KB <= 12.58MB
  float* o_part = (float*)(ws + 2621440);            // 2*8*4096*32*4 = 8388608
  float* l_part = (float*)(ws + 2621440 + 8388608);  // 2*8*4096*4    = 262144

  k_prep_w<<<512, 256, 0, stream>>>(w_pw, w_lin, wpw_h, wlin_h, kmax_bits);
  k_transpose_x<<<1024, 256, 0, stream>>>(x, xt);
  k_gemm_qkv<<<768, 256, 0, stream>>>(wpw_h, xt, b_pw, qkv);
  k_dwconv<<<768, 256, 0, stream>>>(qkv, w_dw, b_dw, q_nm, k_nm, v_cm);
  k_norms<<<256, 256, 0, stream>>>(q_nm, k_nm, q_bound, kmax_bits);
  k_attn<<<512, 512, 0, stream>>>(q_nm, k_nm, v_cm, q_bound, kmax_bits,
                                  o_part, l_part);
  k_norm_o<<<1024, 256, 0, stream>>>(o_part, l_part, nx);
  k_gemm_proj<<<256, 256, 0, stream>>>(wlin_h, nx, b_lin, x, out);
}